// Round 13
// baseline (548.904 us; speedup 1.0000x reference)
//
#include <hip/hip_runtime.h>

// ---------------------------------------------------------------------------
// SPPF + criss-cross attention, MI355X bf16-MFMA pipeline.
// Algebra: W2·(γ(outH+outW)+cat) = (W2Wv)·(γ·mixed) + W2·cat + γ·W2·b_v.
// GEMM core: 256x256 tile, BK=32 double-buffer, 64 KiB LDS -> 2 blocks/CU
// (16 waves/CU co-residency fills barrier stalls, m114). Same tile size keeps
// arithmetic intensity of the r12 version; accumulation order unchanged.
// ---------------------------------------------------------------------------

typedef short bf16x8 __attribute__((ext_vector_type(8)));
typedef float f32x4  __attribute__((ext_vector_type(4)));

#define DEV __device__ __forceinline__

DEV float bf2f(unsigned short u) {
    unsigned int i = ((unsigned int)u) << 16;
    float f; __builtin_memcpy(&f, &i, 4); return f;
}
DEV unsigned short f2bf(float f) {
    unsigned int i; __builtin_memcpy(&i, &f, 4);
    unsigned int r = i + 0x7FFFu + ((i >> 16) & 1u);
    return (unsigned short)(r >> 16);
}
DEV float fsilu(float v) { return v / (1.f + __expf(-v)); }

#define GLL(gsrc, ldst)                                                        \
    __builtin_amdgcn_global_load_lds(                                          \
        (const __attribute__((address_space(1))) unsigned int*)(gsrc),         \
        (__attribute__((address_space(3))) unsigned int*)(ldst), 16, 0, 0)

#define MFMA(a, b, c) __builtin_amdgcn_mfma_f32_16x16x32_bf16((a), (b), (c), 0, 0, 0)

#define SBAR do {                                                              \
    __builtin_amdgcn_sched_barrier(0);                                         \
    __builtin_amdgcn_s_barrier();                                              \
    __builtin_amdgcn_sched_barrier(0); } while (0)
#define LGKM0 do {                                                             \
    asm volatile("s_waitcnt lgkmcnt(0)" ::: "memory");                         \
    __builtin_amdgcn_sched_barrier(0); } while (0)
#define VMC(n) do {                                                            \
    asm volatile("s_waitcnt vmcnt(" #n ")" ::: "memory");                      \
    __builtin_amdgcn_sched_barrier(0); } while (0)

// ---------------------------------------------------------------------------
// GEMM core: 256x256 NT, BK=32, double-buffered (2 x 16KiB per operand).
// Per K-tile: ds_reads(db) -> lgkm0 -> barrier (WAR close) -> stage kt+2
// into db (4 GLL) -> 32 MFMA -> vmcnt(4) (tile kt+1 landed) -> barrier.
// EPI: 0=BN+SiLU bf16, 1=+bias bf16, 4=BN+SiLU fp32 NCHW. Dual K-source.
// ---------------------------------------------------------------------------
template <int EPI, bool DUAL>
DEV void gemm_core(
    unsigned short (&Ash)[2][8192], unsigned short (&Bsh)[2][8192],
    int bx, int by,
    const unsigned short* __restrict__ A, const unsigned short* __restrict__ B,
    const unsigned short* __restrict__ A2, const unsigned short* __restrict__ B2,
    int lda, int ldb, int K1, int K2,
    void* __restrict__ outp, int ldo,
    const float* __restrict__ p0, const float* __restrict__ p1)
{
    const int tid = threadIdx.x, lane = tid & 63, wave = tid >> 6;
    const int wm = wave >> 2, wn = wave & 3;           // 2M x 4N wave grid
    const long tile_m = (long)bx * 256;
    const long tile_n = (long)by * 256;
    const int r0 = tid >> 2;                            // rows 0..127
    const int ke0 = ((tid & 3) * 8) ^ (16 * ((r0 >> 3) & 1));  // swizzled k-el
    const unsigned short* As0 = A + (tile_m + r0) * (long)lda + ke0;
    const unsigned short* As1 = A + (tile_m + r0 + 128) * (long)lda + ke0;
    const unsigned short* Bs0 = B + (tile_n + r0) * (long)ldb + ke0;
    const unsigned short* Bs1 = B + (tile_n + r0 + 128) * (long)ldb + ke0;
    const unsigned short* Cs0 = DUAL ? A2 + (tile_m + r0) * (long)lda + ke0 : As0;
    const unsigned short* Cs1 = DUAL ? A2 + (tile_m + r0 + 128) * (long)lda + ke0 : As1;
    const unsigned short* Ds0 = DUAL ? B2 + (tile_n + r0) * (long)ldb + ke0 : Bs0;
    const unsigned short* Ds1 = DUAL ? B2 + (tile_n + r0 + 128) * (long)ldb + ke0 : Bs1;
    const int dst0 = wave * 512;          // element offset; HW adds lane*16B
    const int dst1 = 4096 + wave * 512;
    const int arow = lane & 15;
    const int kgs = ((lane >> 4) << 3) ^ (16 * ((arow >> 3) & 1)); // swizzled
    f32x4 acc[8][4] = {};
    bf16x8 a[8], b[4];
    const int nt1 = K1 >> 5;
    const int nt = nt1 + (DUAL ? (K2 >> 5) : 0);

#define PA0(t) ((DUAL && (t) >= nt1) ? Cs0 + (long)((t) - nt1) * 32 : As0 + (long)(t) * 32)
#define PA1(t) ((DUAL && (t) >= nt1) ? Cs1 + (long)((t) - nt1) * 32 : As1 + (long)(t) * 32)
#define PB0(t) ((DUAL && (t) >= nt1) ? Ds0 + (long)((t) - nt1) * 32 : Bs0 + (long)(t) * 32)
#define PB1(t) ((DUAL && (t) >= nt1) ? Ds1 + (long)((t) - nt1) * 32 : Bs1 + (long)(t) * 32)
#define STG(bf, t) do {                                                        \
    GLL(PA0(t), &Ash[bf][dst0]);                                               \
    GLL(PA1(t), &Ash[bf][dst1]);                                               \
    GLL(PB0(t), &Bsh[bf][dst0]);                                               \
    GLL(PB1(t), &Bsh[bf][dst1]); } while (0)
#define LDA8(db) do { _Pragma("unroll")                                        \
    for (int m = 0; m < 8; ++m)                                                \
        a[m] = *(const bf16x8*)&Ash[db][(wm * 128 + m * 16 + arow) * 32 + kgs];\
    } while (0)
#define LDB1(db, n, slot)                                                      \
    b[slot] = *(const bf16x8*)&Bsh[db][(wn * 64 + (n) * 16 + arow) * 32 + kgs]
#define MMA2(lo) do {                                                          \
    __builtin_amdgcn_s_setprio(1);                                             \
    _Pragma("unroll")                                                          \
    for (int m = 0; m < 8; ++m) {                                              \
        acc[m][lo]     = MFMA(a[m], b[lo],     acc[m][lo]);                    \
        acc[m][lo + 1] = MFMA(a[m], b[lo + 1], acc[m][lo + 1]);                \
    }                                                                          \
    __builtin_amdgcn_s_setprio(0); } while (0)

    // prologue: tiles 0,1 into buffers 0,1 (8 GLL); vmcnt(4) => tile0 ready
    STG(0, 0);
    STG(1, (1 < nt) ? 1 : 0);
    VMC(4);
    SBAR;

    for (int kt = 0; kt < nt; ++kt) {
        const int db = kt & 1;
        const int t2c = (kt + 2 < nt) ? kt + 2 : nt - 1;   // clamped tail
        LDA8(db);
        LDB1(db, 0, 0); LDB1(db, 1, 1); LDB1(db, 2, 2); LDB1(db, 3, 3);
        LGKM0;              // own-wave frags resident
        SBAR;               // all waves done reading db -> safe to overwrite
        STG(db, t2c);       // 4 GLL -> db (tile kt+2)
        MMA2(0);
        MMA2(2);
        VMC(4);             // oldest-first: tile kt+1 (in db^1) landed
        SBAR;
    }
    VMC(0);                 // drain tail prefetches before epilogue

    const int rbase = (lane >> 4) << 2;
#pragma unroll
    for (int n = 0; n < 4; ++n) {
        const int gcol = (int)tile_n + wn * 64 + n * 16 + arow;
        const float s0 = p0[gcol];
        const float s1 = (EPI != 1) ? p1[gcol] : 0.f;
#pragma unroll
        for (int m = 0; m < 8; ++m) {
            const long grow0 = tile_m + wm * 128 + m * 16 + rbase;
            if (EPI == 4) {
                const long bb = grow0 >> 12, pix = grow0 & 4095;
                float4 o4;
#pragma unroll
                for (int r = 0; r < 4; ++r) {
                    float v = acc[m][n][r] * s0 + s1;
                    ((float*)&o4)[r] = fsilu(v);
                }
                *(float4*)&((float*)outp)[((bb * 512 + gcol)) * 4096 + pix] = o4;
            } else {
#pragma unroll
                for (int r = 0; r < 4; ++r) {
                    float v = acc[m][n][r];
                    if (EPI != 1) { v = v * s0 + s1; v = fsilu(v); }
                    else          { v += s0; }
                    ((unsigned short*)outp)[(grow0 + r) * ldo + gcol] = f2bf(v);
                }
            }
        }
    }
#undef PA0
#undef PA1
#undef PB0
#undef PB1
#undef STG
#undef LDA8
#undef LDB1
#undef MMA2
}

// ---------------------------------------------------------------------------
// gemm_pair: grid = 256 linear. Pair-XCD swizzle: the two n-tiles sharing an
// A-panel land on the same XCD (ids 8 apart). M = 128 m-tiles, N = 2.
// ---------------------------------------------------------------------------
template <int EPI, bool DUAL>
__global__ __launch_bounds__(512, 2) void gemm_pair(
    const unsigned short* __restrict__ A, const unsigned short* __restrict__ B,
    const unsigned short* __restrict__ A2, const unsigned short* __restrict__ B2,
    int lda, int ldb, int K1, int K2,
    void* __restrict__ outp, int ldo,
    const float* __restrict__ p0, const float* __restrict__ p1)
{
    __shared__ __align__(16) unsigned short Ash[2][8192];
    __shared__ __align__(16) unsigned short Bsh[2][8192];
    const int bid = blockIdx.x;
    const int xcd = bid & 7, idx = bid >> 3;
    const int m = xcd + 8 * (idx >> 1);
    const int n = idx & 1;
    gemm_core<EPI, DUAL>(Ash, Bsh, m, n, A, B, A2, B2, lda, ldb, K1, K2,
                         outp, ldo, p0, p1);
}

// ---------------------------------------------------------------------------
// gemm_wcv1: merged launch, 142 blocks. [0,14) = w2g (2x7 tiles, EPI=1),
// [14,142) = cv1 (128x1 tiles, EPI=0). Runs concurrently.
// ---------------------------------------------------------------------------
__global__ __launch_bounds__(512, 2) void gemm_wcv1(
    const unsigned short* __restrict__ wc2, const unsigned short* __restrict__ wvT,
    unsigned short* __restrict__ w2g, const float* __restrict__ zeros,
    const unsigned short* __restrict__ xT, const unsigned short* __restrict__ wb1,
    unsigned short* __restrict__ catT,
    const float* __restrict__ sc1, const float* __restrict__ sh1)
{
    __shared__ __align__(16) unsigned short Ash[2][8192];
    __shared__ __align__(16) unsigned short Bsh[2][8192];
    const int bid = blockIdx.x;
    if (bid < 14) {
        const int bx = bid / 7, by = bid % 7;
        gemm_core<1, false>(Ash, Bsh, bx, by, wc2, wvT, wc2, wvT,
                            1792, 1792, 1792, 0, w2g, 1792, zeros, nullptr);
    } else {
        const int bx = bid - 14;
        gemm_core<0, false>(Ash, Bsh, bx, 0, xT, wb1, xT, wb1,
                            512, 512, 512, 0, catT, 1792, sc1, sh1);
    }
}

// ---------------------------------------------------------------------------
// prep_all: one launch, 6416 blocks x 256 threads, partitioned:
//   [0,4096)    transpose_x  (8,512,4096) fp32 -> xT (32768,512) bf16
//   [4096,4880) transpose_w  v_w -> wvT bf16
//   [4880,5904) prep         weights->bf16, qk stack, cv1 BN, qkb, zeros
//   [5904,6416) sh2          dot(W2[i],b_v) reduce + BN shift
// ---------------------------------------------------------------------------
__global__ __launch_bounds__(256) void prep_all(
    const float* __restrict__ x, unsigned short* __restrict__ xT,
    const float* __restrict__ v_w, unsigned short* __restrict__ wvT,
    const float* __restrict__ cv1_w, const float* __restrict__ cv1_g,
    const float* __restrict__ cv1_b, const float* __restrict__ cv1_m,
    const float* __restrict__ cv1_v,
    const float* __restrict__ q_w, const float* __restrict__ q_b,
    const float* __restrict__ k_w, const float* __restrict__ k_b,
    const float* __restrict__ cv2_w,
    unsigned short* __restrict__ wb1, unsigned short* __restrict__ wqk,
    unsigned short* __restrict__ wc2,
    float* __restrict__ sc1, float* __restrict__ sh1,
    float* __restrict__ qkb, float* __restrict__ zeros,
    const float* __restrict__ cv2_g, const float* __restrict__ cv2_b,
    const float* __restrict__ cv2_m, const float* __restrict__ cv2_v,
    const float* __restrict__ v_b, const float* __restrict__ gamma,
    float* __restrict__ sc2, float* __restrict__ sh2)
{
    const int bid = blockIdx.x, tid = threadIdx.x;
    __shared__ __align__(16) float tile[64][65];
    if (bid < 4096) {
        int nt = bid & 63, ct = (bid >> 6) & 7, b = bid >> 9;
        int n0 = nt * 64, c0 = ct * 64;
#pragma unroll
        for (int it = 0; it < 16; ++it) {
            int idx = tid + it * 256;
            int r = idx >> 6, cc = idx & 63;
            tile[r][cc] = x[((long)(b * 512 + c0 + r)) * 4096 + n0 + cc];
        }
        __syncthreads();
#pragma unroll
        for (int it = 0; it < 16; ++it) {
            int idx = tid + it * 256;
            int r = idx >> 6, cc = idx & 63;
            xT[((long)(b * 4096 + n0 + r)) * 512 + c0 + cc] = f2bf(tile[cc][r]);
        }
    } else if (bid < 4880) {
        int id = bid - 4096;
        int tx = id % 28, ty = id / 28;
#pragma unroll
        for (int it = 0; it < 16; ++it) {
            int idx = tid + it * 256;
            int r = idx >> 6, cc = idx & 63;
            tile[r][cc] = v_w[((long)(ty * 64 + r)) * 1792 + tx * 64 + cc];
        }
        __syncthreads();
#pragma unroll
        for (int it = 0; it < 16; ++it) {
            int idx = tid + it * 256;
            int r = idx >> 6, cc = idx & 63;
            wvT[((long)(tx * 64 + r)) * 1792 + ty * 64 + cc] = f2bf(tile[cc][r]);
        }
    } else if (bid < 5904) {
        for (int i = (bid - 4880) * 256 + tid; i < 917504; i += 1024 * 256) {
            wc2[i] = f2bf(cv2_w[i]);
            int row = i / 1792;
            int col = i - row * 1792;
            float qv = (row < 224) ? q_w[i]
                       : (row < 448) ? k_w[(row - 224) * 1792 + col] : 0.f;
            wqk[i] = f2bf(qv);
            if (i < 131072) wb1[i] = f2bf(cv1_w[i]);
            if (i < 1792) zeros[i] = 0.f;
            if (i < 512) qkb[i] = (i < 224) ? q_b[i] : (i < 448 ? k_b[i - 224] : 0.f);
            if (i < 256) {
                float sc = cv1_g[i] * rsqrtf(cv1_v[i] + 1e-5f);
                sc1[i] = sc; sh1[i] = cv1_b[i] - cv1_m[i] * sc;
            }
        }
    } else {
        const int i = bid - 5904;
        float* red = &tile[0][0];
        float s = 0.f;
        for (int k = tid; k < 1792; k += 256) s += cv2_w[i * 1792 + k] * v_b[k];
        red[tid] = s;
        __syncthreads();
#pragma unroll
        for (int off = 128; off > 0; off >>= 1) {
            if (tid < off) red[tid] += red[tid + off];
            __syncthreads();
        }
        if (tid == 0) {
            float sc = cv2_g[i] * rsqrtf(cv2_v[i] + 1e-5f);
            sc2[i] = sc;
            sh2[i] = cv2_b[i] - cv2_m[i] * sc + sc * gamma[0] * red[0];
        }
    }
}

// ---------------------------------------------------------------------------
// pool_h body per radius (van Herk max + sliding sum along w).
// ---------------------------------------------------------------------------
template <int I>
DEV void pool_h_body(const unsigned short* x1s, unsigned short* pool,
                     int c, int w0, long obase)
{
    constexpr int R = 2 * (I + 1);
    constexpr int K = 2 * R + 1;
    unsigned short* qm = pool + (long)I * 32768 * 256;
    unsigned short* qs = pool + (long)(I + 3) * 32768 * 256;
    float pre[32];
    {
        float run = -1e30f;
        int ph = (w0 + 2 * R - (K - 1)) % K;
#pragma unroll
        for (int t = 0; t < 32 + K - 1; ++t) {
            int p = w0 + R - (K - 1) + t;
            if (ph == 0) run = -1e30f;
            float v = ((unsigned)p < 64u) ? bf2f(x1s[p * 256 + c]) : -1e30f;
            run = fmaxf(run, v);
            if (t >= K - 1) pre[t - (K - 1)] = run;
            ph = (ph + 1 == K) ? 0 : ph + 1;
        }
    }
    {
        float run = -1e30f;
        int ph = (w0 + 31 + (K - 1)) % K;
#pragma unroll
        for (int t = 0; t < 32 + K - 1; ++t) {
            int s = w0 + 31 - R + (K - 1) - t;
            if (ph == K - 1) run = -1e30f;
            float v = ((unsigned)s < 64u) ? bf2f(x1s[s * 256 + c]) : -1e30f;
            run = fmaxf(run, v);
            if (t >= K - 1) {
                int w = s + R;
                qm[obase + (long)w * 16384] =
                    f2bf(fmaxf(run, pre[31 + (K - 1) - t]));
            }
            ph = (ph == 0) ? K - 1 : ph - 1;
        }
    }
    {
        float s = 0.f;
        int lo0 = (w0 - R >= 0) ? w0 - R : 0;
        int hi0 = (w0 + R <= 63) ? w0 + R : 63;
        for (int d = lo0; d <= hi0; ++d) s += bf2f(x1s[d * 256 + c]);
        for (int ww = 0; ww < 32; ++ww) {
            int w = w0 + ww;
            qs[obase + (long)w * 16384] = f2bf(s);
            if (w + 1 + R <= 63) s += bf2f(x1s[(w + 1 + R) * 256 + c]);
            if (w - R >= 0)      s -= bf2f(x1s[(w - R) * 256 + c]);
        }
    }
}

__global__ __launch_bounds__(512) void pool_h_all(
    const unsigned short* __restrict__ catT, unsigned short* __restrict__ pool)
{
    const int b = blockIdx.x >> 6, h = blockIdx.x & 63;
    __shared__ __align__(16) unsigned short x1s[64 * 256];
    const int tid = threadIdx.x, lane = tid & 63, wave = tid >> 6;
    const long nb = (long)b * 4096 + h * 64;
#pragma unroll
    for (int j = 0; j < 4; ++j) {
        int chunk = j * 8 + wave;
        int o = chunk * 1024 + lane * 16;
        int e = o >> 1, w = e >> 8, c = e & 255;
        GLL(catT + (nb + w) * 1792 + c, (char*)x1s + chunk * 1024);
    }
    __syncthreads();
    const int c = tid & 255, wg = tid >> 8;
    const int w0 = wg * 32;
    const long obase = ((long)b * 4096 + h) * 256 + c;
    pool_h_body<0>(x1s, pool, c, w0, obase);
    pool_h_body<1>(x1s, pool, c, w0, obase);
    pool_h_body<2>(x1s, pool, c, w0, obase);
}

// ---------------------------------------------------------------------------
// pool_v body per radius; slabs staged by caller.
// ---------------------------------------------------------------------------
template <int I>
DEV void pool_v_body(const unsigned short* mslab, const unsigned short* sslab,
                     unsigned short* catT, int c, int h0, long dbase)
{
    constexpr int R = 2 * (I + 1);
    constexpr int K = 2 * R + 1;
    constexpr float SCL = (I == 0) ? (1.f / 25.f)
                        : (I == 1) ? (1.f / 81.f) : (1.f / 169.f);
    constexpr int MAXD = 256 * (I + 1);
    constexpr int SUMD = 1536 - 256 * I;
    float pre[32];
    {
        float run = -1e30f;
        int ph = (h0 + 2 * R - (K - 1)) % K;
#pragma unroll
        for (int t = 0; t < 32 + K - 1; ++t) {
            int p = h0 + R - (K - 1) + t;
            if (ph == 0) run = -1e30f;
            float v = ((unsigned)p < 64u) ? bf2f(mslab[p * 128 + c]) : -1e30f;
            run = fmaxf(run, v);
            if (t >= K - 1) pre[t - (K - 1)] = run;
            ph = (ph + 1 == K) ? 0 : ph + 1;
        }
    }
    {
        float run = -1e30f;
        int ph = (h0 + 31 + (K - 1)) % K;
#pragma unroll
        for (int t = 0; t < 32 + K - 1; ++t) {
            int s = h0 + 31 - R + (K - 1) - t;
            if (ph == K - 1) run = -1e30f;
            float v = ((unsigned)s < 64u) ? bf2f(mslab[s * 128 + c]) : -1e30f;
            run = fmaxf(run, v);
            if (t >= K - 1) {
                int h = s + R;
                catT[dbase + MAXD + (long)h * (64 * 1792)] =
                    f2bf(fmaxf(run, pre[31 + (K - 1) - t]));
            }
            ph = (ph == 0) ? K - 1 : ph - 1;
        }
    }
    {
        float s = 0.f;
        int lo0 = (h0 - R >= 0) ? h0 - R : 0;
        int hi0 = (h0 + R <= 63) ? h0 + R : 63;
        for (int d = lo0; d <= hi0; ++d) s += bf2f(sslab[d * 128 + c]);
        for (int hh = 0; hh < 32; ++hh) {
            int h = h0 + hh;
            catT[dbase + SUMD + (long)h * (64 * 1792)] = f2bf(s * SCL);
            if (h + 1 + R <= 63) s += bf2f(sslab[(h + 1 + R) * 128 + c]);
            if (h - R >= 0)      s -= bf2f(sslab[(h - R) * 128 + c]);
        }
    }
}

__global__ __launch_bounds__(256) void pool_v_all(
    const unsigned short* __restrict__ pool, unsigned short* __restrict__ catT)
{
    const int s6 = blockIdx.y;
    const int bid = blockIdx.x;
    const int chh = bid & 1, w = (bid >> 1) & 63, b = bid >> 7;
    const int c0 = chh * 128;
    __shared__ __align__(16) unsigned short mslab[64 * 128];
    __shared__ __align__(16) unsigned short sslab[64 * 128];
    const int tid = threadIdx.x, lane = tid & 63, wave = tid >> 6;
    const long sbase = ((long)b * 4096 + (long)w * 64) * 256 + c0;
    const unsigned short* msrc = pool + (long)s6 * 32768 * 256 + sbase;
    const unsigned short* ssrc = pool + (long)(s6 + 3) * 32768 * 256 + sbase;
#pragma unroll
    for (int j = 0; j < 4; ++j) {
        int o = j * 4096 + wave * 1024 + lane * 16;
        int hh = o >> 8, ce = (o & 255) >> 1;
        GLL(msrc + hh * 256 + ce, (char*)mslab + (j * 4096 + wave * 1024));
        GLL(ssrc + hh * 256 + ce, (char*)sslab + (j * 4096 + wave * 1024));
    }
    __syncthreads();
    const int c = tid & 127, hg = tid >> 7;
    const int h0 = hg * 32;
    const long dbase = ((long)b * 4096 + w) * 1792 + c0 + c;
    if (s6 == 0)      pool_v_body<0>(mslab, sslab, catT, c, h0, dbase);
    else if (s6 == 1) pool_v_body<1>(mslab, sslab, catT, c, h0, dbase);
    else              pool_v_body<2>(mslab, sslab, catT, c, h0, dbase);
}

// ---------------------------------------------------------------------------
// S1: eH scores, block = (b, w).
// ---------------------------------------------------------------------------
__global__ __launch_bounds__(256) void scores_h(
    const unsigned short* __restrict__ qk, float* __restrict__ attHlog)
{
    const int b = blockIdx.x >> 6, w = blockIdx.x & 63;
    __shared__ __align__(16) unsigned short Qs[64 * 232];
    __shared__ __align__(16) unsigned short Ks[64 * 232];
    const int tid = threadIdx.x, lane = tid & 63, wave = tid >> 6;
#pragma unroll
    for (int j = 0; j < 14; ++j) {
        int idx = tid + j * 256;
        int s = idx >= 1792;
        int id2 = idx - s * 1792;
        int row = id2 / 28, cb = id2 - row * 28;
        bf16x8 v = *(const bf16x8*)(qk + ((long)b * 4096 + row * 64 + w) * 512 +
                                    s * 224 + cb * 8);
        *(bf16x8*)((s ? Ks : Qs) + row * 232 + cb * 8) = v;
    }
    __syncthreads();
    const int m0 = wave * 16, arow = lane & 15, kc = (lane >> 4) << 3;
    f32x4 acc[4] = {};
#pragma unroll
    for (int ks = 0; ks < 7; ++ks) {
        bf16x8 af = *(const bf16x8*)(Qs + (m0 + arow) * 232 + ks * 32 + kc);
#pragma unroll
        for (int nf = 0; nf < 4; ++nf) {
            bf16x8 bv = *(const bf16x8*)(Ks + (nf * 16 + arow) * 232 + ks * 32 + kc);
            acc[nf] = MFMA(af, bv, acc[nf]);
        }
    }
    const int rb = (lane >> 4) << 2;
#pragma unroll
    for (int nf = 0; nf < 4; ++nf) {
        int g = nf * 16 + arow;
#pragma unroll
        for (int r = 0; r < 4; ++r) {
            int h = m0 + rb + r;
            float v = acc[nf][r];
            if (g == h) v = -1e30f;
            attHlog[((long)(b * 64 + h) * 64 + w) * 64 + g] = v;
        }
    }
}

// ---------------------------------------------------------------------------
// S2: eW scores + fused softmax over concat([eH, eW], 128). block = (b, h).
// ---------------------------------------------------------------------------
__global__ __launch_bounds__(256) void scores_w_softmax(
    const unsigned short* __restrict__ qk, const float* __restrict__ attHlog,
    unsigned short* __restrict__ att)
{
    const int b = blockIdx.x >> 6, h = blockIdx.x & 63;
    __shared__ __align__(16) unsigned short Qs[64 * 232];
    __shared__ __align__(16) unsigned short Ks[64 * 232];
    __shared__ float ews[64 * 65];
    const int tid = threadIdx.x, lane = tid & 63, wave = tid >> 6;
    const long nbase = (long)b * 4096 + h * 64;
#pragma unroll
    for (int j = 0; j < 14; ++j) {
        int idx = tid + j * 256;
        int s = idx >= 1792;
        int id2 = idx - s * 1792;
        int row = id2 / 28, cb = id2 - row * 28;
        bf16x8 v = *(const bf16x8*)(qk + (nbase + row) * 512 + s * 224 + cb * 8);
        *(bf16x8*)((s ? Ks : Qs) + row * 232 + cb * 8) = v;
    }
    __syncthreads();
    const int m0 = wave * 16, arow = lane & 15, kc = (lane >> 4) << 3;
    f32x4 acc[4] = {};
#pragma unroll
    for (int ks = 0; ks < 7; ++ks) {
        bf16x8 af = *(const bf16x8*)(Qs + (m0 + arow) * 232 + ks * 32 + kc);
#pragma unroll
        for (int nf = 0; nf < 4; ++nf) {
            bf16x8 bv = *(const bf16x8*)(Ks + (nf * 16 + arow) * 232 + ks * 32 + kc);
            acc[nf] = MFMA(af, bv, acc[nf]);
        }
    }
    const int rb = (lane >> 4) << 2;
#pragma unroll
    for (int nf = 0; nf < 4; ++nf)
#pragma unroll
        for (int r = 0; r < 4; ++r)
            ews[(m0 + rb + r) * 65 + nf * 16 + arow] = acc[nf][r];
    __syncthreads();
    const int wl = tid >> 2, p = tid & 3;
    float eh[16], ew[16];
    const float* hrow = attHlog + ((long)(b * 64 + h) * 64 + wl) * 64 + p * 16;
#pragma unroll
    for (int j = 0; j < 16; ++j) eh[j] = hrow[j];
#pragma unroll
    for (int j = 0; j < 16; ++j) ew[j] = ews[wl * 65 + p * 16 + j];
    float mx = -1e30f;
#pragma unroll
    for (int j = 0; j < 16; ++j) { mx = fmaxf(mx, eh[j]); mx = fmaxf(mx, ew[j]); }
    mx = fmaxf(mx, __shfl_xor(mx, 1));
    mx = fmaxf(mx, __shfl_xor(mx, 2));
    float sm = 0.f;
#pragma unroll
    for (int j = 0; j < 16; ++j) {
        eh[j] = __expf(eh[j] - mx); sm += eh[j];
        ew[j] = __expf(ew[j] - mx); sm += ew[j];
    }
    sm += __shfl_xor(sm, 1);
    sm += __shfl_xor(sm, 2);
    float inv = 1.f / sm;
    unsigned short* orow = att + ((long)(b * 64 + h) * 64 + wl) * 128;
#pragma unroll
    for (int j = 0; j < 16; ++j) orow[p * 16 + j] = f2bf(eh[j] * inv);
#pragma unroll
    for (int j = 0; j < 16; ++j) orow[64 + p * 16 + j] = f2bf(ew[j] * inv);
}

// ---------------------------------------------------------------------------
// apply_att on cat directly: grid 2048 = b(8) x i(64) x chunk(4).
//   MODE 0: mixed = attH-mix(cat).   MODE 1: mixed = gam*(mixed + attW-mix).
// ---------------------------------------------------------------------------
template <int MODE>
__global__ __launch_bounds__(256) void apply_att(
    const unsigned short* __restrict__ att, const unsigned short* __restrict__ vsrc,
    unsigned short* __restrict__ mixed, const float* __restrict__ gamma)
{
    const int ch = blockIdx.x & 3;
    const int i  = (blockIdx.x >> 2) & 63;
    const int b  = blockIdx.x >> 8;
    const int c0 = ch * 448;
    __shared__ __align__(16) unsigned short As[64 * 72];
    __shared__ __align__(16) unsigned short Vs[64 * 448];
    const int tid = threadIdx.x, lane = tid & 63, wave = tid >> 6;
#pragma unroll
    for (int j = 0; j < 2; ++j) {
        int idx = tid + j * 256;
        int hh = idx >> 3, cb = idx & 7;
        long pos = (MODE == 0) ? ((long)(b * 64 + hh) * 64 + i)
                               : ((long)(b * 64 + i) * 64 + hh);
        bf16x8 v = *(const bf16x8*)(att + pos * 128 + MODE * 64 + cb * 8);
        *(bf16x8*)(As + hh * 72 + cb * 8) = v;
    }
#pragma unroll
    for (int j = 0; j < 14; ++j) {
        int idx = tid + j * 256;
        int g = idx / 56, cb = idx - g * 56;
        long n = (MODE == 0) ? ((long)b * 4096 + g * 64 + i)
                             : ((long)b * 4096 + i * 64 + g);
        bf16x8 v = *(const bf16x8*)(vsrc + n * 1792 + c0 + cb * 8);
        int sw = (g >> 3) & 7;
        *(bf16x8*)(Vs + g * 448 + ((cb ^ sw) << 3)) = v;
    }
    __syncthreads();
    const int arow = lane & 15, kc8 = (lane >> 4) << 3;
    const int rb = (lane >> 4) << 2;
    f32x4 acc[4][7] = {};
#pragma unroll
    for (int ks = 0; ks < 2; ++ks) {
        const int k0 = ks * 32;
        bf16x8 af[4];
#pragma unroll
        for (int m = 0; m < 4; ++m)
            af[m] = *(const bf16x8*)(As + (m * 16 + arow) * 72 + k0 + kc8);
        const int g0 = k0 + kc8;
        const int sw = (g0 >> 3) & 7;
#pragma unroll
        for (int nf = 0; nf < 7; ++nf) {
            int cl = wave * 112 + nf * 16 + arow;
            int cb = cl >> 3, clo = cl & 7;
            const unsigned short* pp = Vs + g0 * 448 + ((cb ^ sw) << 3) + clo;
            bf16x8 bv;
#pragma unroll
            for (int j = 0; j < 8; ++j) bv[j] = (short)pp[j * 448];
#pragma unroll
            for (int m = 0; m < 4; ++m)
                acc[m][nf] = MFMA(af[m], bv, acc[m][nf]);
        }
    }
    const float gam = gamma[0];
#pragma unroll
    for (int nf = 0; nf < 7; ++nf) {
        const int c = c0 + wave * 112 + nf * 16 + arow;
#pragma unroll
        for (int m = 0; m < 4; ++m) {
#pragma unroll
            for (int r = 0; r < 4; ++r) {
                const int rl = m * 16 + rb + r;
                long n = (MODE == 0) ? ((long)b * 4096 + rl * 64 + i)
                                     : ((long)b * 4096 + i * 64 + rl);
                long idx2 = n * 1792 + c;
                if (MODE == 0) {
                    mixed[idx2] = f2bf(acc[m][nf][r]);
                } else {
                    float pv = bf2f(mixed[idx2]);
                    mixed[idx2] = f2bf(gam * (acc[m][nf][r] + pv));
                }
            }
        }
    }
}

// ---------------------------------------------------------------------------
// launcher
// ---------------------------------------------------------------------------
extern "C" void kernel_launch(void* const* d_in, const int* in_sizes, int n_in,
                              void* d_out, int out_size, void* d_ws, size_t ws_size,
                              hipStream_t stream)
{
    const float* x     = (const float*)d_in[0];
    const float* cv1_w = (const float*)d_in[1];
    const float* cv1_g = (const float*)d_in[2];
    const float* cv1_b = (const float*)d_in[3];
    const float* cv1_m = (const float*)d_in[4];
    const float* cv1_v = (const float*)d_in[5];
    const float* q_w   = (const float*)d_in[6];
    const float* q_b   = (const float*)d_in[7];
    const float* k_w   = (const float*)d_in[8];
    const float* k_b   = (const float*)d_in[9];
    const float* v_w   = (const float*)d_in[10];
    const float* v_b   = (const float*)d_in[11];
    const float* gamma = (const float*)d_in[12];
    const float* cv2_w = (const float*)d_in[13];
    const float* cv2_g = (const float*)d_in[14];
    const float* cv2_b = (const float*)d_in[15];
    const float* cv2_m = (const float*)d_in[16];
    const float* cv2_v = (const float*)d_in[17];

    char* ws = (char*)d_ws;
    // ---- workspace map (total ~230 MiB) ----
    unsigned short* wb1  = (unsigned short*)(ws + 0);          //  256x512
    unsigned short* wqk  = (unsigned short*)(ws + 262144);     //  512x1792
    unsigned short* wc2  = (unsigned short*)(ws + 2097152);    //  512x1792
    unsigned short* w2g  = (unsigned short*)(ws + 3932160);    //  512x1792 (W2*Wv)
    float* sc1           = (float*)(ws + 5767168);
    float* sh1           = (float*)(ws + 5775360);
    float* sc2           = (float*)(ws + 5783552);
    float* sh2           = (float*)(ws + 5791744);
    float* qkb           = (float*)(ws + 5799936);
    float* zeros         = (float*)(ws + 5808128);             // 1792 fp32
    unsigned short* catT = (unsigned short*)(ws + 6291456);    // 32768x1792, live to end
    const long C_OFF = 123731968;                              // catT end
    unsigned short* xT    = (unsigned short*)(ws + C_OFF);            // ph1: 32 MiB
    unsigned short* wvT   = (unsigned short*)(ws + C_OFF + 33554432); // ph1: 6.1 MiB
    unsigned short* poolb = (unsigned short*)(ws + C_OFF);            // ph2: 96 MiB
    unsigned short* mixed = (unsigned short*)(ws + C_OFF);            // ph3-4: 112 MiB
    // d_out (64 MB) time-shared: qk[0,32M) + attHlog[32M,40M) + attb[40M,48M)
    unsigned short* qk    = (unsigned short*)d_out;
    float* attHlog        = (float*)((char*)d_out + 33554432);
    unsigned short* attb  = (unsigned short*)((char*)d_out + 41943040);

    // all independent preprocessing in ONE launch
    prep_all<<<6416, 256, 0, stream>>>(
        x, xT, v_w, wvT,
        cv1_w, cv1_g, cv1_b, cv1_m, cv1_v, q_w, q_b, k_w, k_b, cv2_w,
        wb1, wqk, wc2, sc1, sh1, qkb, zeros,
        cv2_g, cv2_b, cv2_m, cv2_v, v_b, gamma, sc2, sh2);

    // w2g (14 blocks) runs concurrently with cv1 (128 blocks)
    gemm_wcv1<<<142, 512, 0, stream>>>(wc2, wvT, w2g, zeros,
                                       xT, wb1, catT, sc1, sh1);

    pool_h_all<<<512, 512, 0, stream>>>(catT, poolb);
    pool_v_all<<<dim3(1024, 3), 256, 0, stream>>>(poolb, catT);

    // q,k (stacked, padded to 512 cols) -> qk (in d_out); pair-XCD swizzle
    gemm_pair<1, false><<<256, 512, 0, stream>>>(
        catT, wqk, catT, wqk, 1792, 1792, 1792, 0, qk, 512, qkb, nullptr);

    scores_h<<<512, 256, 0, stream>>>(qk, attHlog);
    scores_w_softmax<<<512, 256, 0, stream>>>(qk, attHlog, attb);

    // criss-cross applied to cat itself -> mixed = gam*(mixH + mixW)
    apply_att<0><<<2048, 256, 0, stream>>>(attb, catT, mixed, gamma);
    apply_att<1><<<2048, 256, 0, stream>>>(attb, catT, mixed, gamma);

    // out = silu(bn( W2Wv.mixed + W2.cat )) -> NCHW fp32; pair-XCD swizzle
    gemm_pair<4, true><<<256, 512, 0, stream>>>(
        mixed, w2g, catT, wc2, 1792, 1792, 1792, 1792, d_out, 0, sc2, sh2);
}

// Round 14
// 513.043 us; speedup vs baseline: 1.0699x; 1.0699x over previous
//
#include <hip/hip_runtime.h>

// ---------------------------------------------------------------------------
// SPPF + criss-cross attention, MI355X bf16-MFMA pipeline.
// Algebra: W2·(γ(outH+outW)+cat) = (W2Wv)·(γ·mixed) + W2·cat + γ·W2·b_v.
// GEMM core: 256x256, BK=64, 8 waves, 4-phase deep staging, vmcnt(4)/K-tile,
// 4 barriers/K-tile (r12 measured-best). Launch fusion: one prep kernel;
// w2g || cv1 merged; qk/final use pair-XCD swizzle.
// ---------------------------------------------------------------------------

typedef short bf16x8 __attribute__((ext_vector_type(8)));
typedef float f32x4  __attribute__((ext_vector_type(4)));

#define DEV __device__ __forceinline__

DEV float bf2f(unsigned short u) {
    unsigned int i = ((unsigned int)u) << 16;
    float f; __builtin_memcpy(&f, &i, 4); return f;
}
DEV unsigned short f2bf(float f) {
    unsigned int i; __builtin_memcpy(&i, &f, 4);
    unsigned int r = i + 0x7FFFu + ((i >> 16) & 1u);
    return (unsigned short)(r >> 16);
}
DEV float fsilu(float v) { return v / (1.f + __expf(-v)); }

#define GLL(gsrc, ldst)                                                        \
    __builtin_amdgcn_global_load_lds(                                          \
        (const __attribute__((address_space(1))) unsigned int*)(gsrc),         \
        (__attribute__((address_space(3))) unsigned int*)(ldst), 16, 0, 0)

#define MFMA(a, b, c) __builtin_amdgcn_mfma_f32_16x16x32_bf16((a), (b), (c), 0, 0, 0)

#define SBAR do {                                                              \
    __builtin_amdgcn_sched_barrier(0);                                         \
    __builtin_amdgcn_s_barrier();                                              \
    __builtin_amdgcn_sched_barrier(0); } while (0)
#define LGKM0 do {                                                             \
    asm volatile("s_waitcnt lgkmcnt(0)" ::: "memory");                         \
    __builtin_amdgcn_sched_barrier(0); } while (0)
#define VMC(n) do {                                                            \
    asm volatile("s_waitcnt vmcnt(" #n ")" ::: "memory");                      \
    __builtin_amdgcn_sched_barrier(0); } while (0)

// ---------------------------------------------------------------------------
// GEMM core (r12): 256x256 NT, BK=64 (2 k-halves), 8 waves, 4-phase, deep
// staging: tile t stages (t+1,kh1) at P1/P2 and (t+2,kh0) at P3/P4; vmcnt(4)
// once per K-tile at P4-end; 4 barriers/K-tile. Dual K-source.
// EPI: 0=BN+SiLU bf16, 1=+bias bf16, 4=BN+SiLU fp32 NCHW.
// ---------------------------------------------------------------------------
template <int EPI, bool DUAL>
DEV void gemm_core(
    unsigned short (&Ash)[2][2][8192], unsigned short (&Bsh)[2][2][8192],
    int bx, int by,
    const unsigned short* __restrict__ A, const unsigned short* __restrict__ B,
    const unsigned short* __restrict__ A2, const unsigned short* __restrict__ B2,
    int lda, int ldb, int K1, int K2,
    void* __restrict__ outp, int ldo,
    const float* __restrict__ p0, const float* __restrict__ p1)
{
    const int tid = threadIdx.x, lane = tid & 63, wave = tid >> 6;
    const int wm = wave >> 2, wn = wave & 3;           // 2M x 4N wave grid
    const long tile_m = (long)bx * 256;
    const long tile_n = (long)by * 256;
    const int r0 = tid >> 2;
    const int ke0 = ((tid & 3) * 8) ^ (16 * ((r0 >> 3) & 1));  // swizzled k-el
    const unsigned short* As0 = A + (tile_m + r0) * (long)lda + ke0;
    const unsigned short* As1 = A + (tile_m + r0 + 128) * (long)lda + ke0;
    const unsigned short* Bs0 = B + (tile_n + r0) * (long)ldb + ke0;
    const unsigned short* Bs1 = B + (tile_n + r0 + 128) * (long)ldb + ke0;
    const unsigned short* Cs0 = DUAL ? A2 + (tile_m + r0) * (long)lda + ke0 : As0;
    const unsigned short* Cs1 = DUAL ? A2 + (tile_m + r0 + 128) * (long)lda + ke0 : As1;
    const unsigned short* Ds0 = DUAL ? B2 + (tile_n + r0) * (long)ldb + ke0 : Bs0;
    const unsigned short* Ds1 = DUAL ? B2 + (tile_n + r0 + 128) * (long)ldb + ke0 : Bs1;
    const int dst0 = wave * 512;
    const int dst1 = 4096 + wave * 512;
    const int arow = lane & 15;
    const int kgs = ((lane >> 4) << 3) ^ (16 * ((arow >> 3) & 1)); // swizzled
    f32x4 acc[8][4] = {};
    bf16x8 a[8], b[4];
    const int nt1 = K1 >> 6;
    const int nt = nt1 + (DUAL ? (K2 >> 6) : 0);

#define PA0(t) ((DUAL && (t) >= nt1) ? Cs0 + (long)((t) - nt1) * 64 : As0 + (long)(t) * 64)
#define PA1(t) ((DUAL && (t) >= nt1) ? Cs1 + (long)((t) - nt1) * 64 : As1 + (long)(t) * 64)
#define PB0(t) ((DUAL && (t) >= nt1) ? Ds0 + (long)((t) - nt1) * 64 : Bs0 + (long)(t) * 64)
#define PB1(t) ((DUAL && (t) >= nt1) ? Ds1 + (long)((t) - nt1) * 64 : Bs1 + (long)(t) * 64)
#define STGA(db, kh, t) do {                                                   \
    GLL(PA0(t) + (kh) * 32, &Ash[db][kh][dst0]);                               \
    GLL(PA1(t) + (kh) * 32, &Ash[db][kh][dst1]); } while (0)
#define STGB(db, kh, t) do {                                                   \
    GLL(PB0(t) + (kh) * 32, &Bsh[db][kh][dst0]);                               \
    GLL(PB1(t) + (kh) * 32, &Bsh[db][kh][dst1]); } while (0)
#define LDA8(db, ks) do { _Pragma("unroll")                                    \
    for (int m = 0; m < 8; ++m)                                                \
        a[m] = *(const bf16x8*)&Ash[db][ks][(wm * 128 + m * 16 + arow) * 32 + kgs]; \
    } while (0)
#define LDB1(db, ks, n, slot)                                                  \
    b[slot] = *(const bf16x8*)&Bsh[db][ks][(wn * 64 + (n) * 16 + arow) * 32 + kgs]
#define MMA2(lo) do {                                                          \
    __builtin_amdgcn_s_setprio(1);                                             \
    _Pragma("unroll")                                                          \
    for (int m = 0; m < 8; ++m) {                                              \
        acc[m][lo]     = MFMA(a[m], b[lo],     acc[m][lo]);                    \
        acc[m][lo + 1] = MFMA(a[m], b[lo + 1], acc[m][lo + 1]);                \
    }                                                                          \
    __builtin_amdgcn_s_setprio(0); } while (0)

    // prologue: (0,kh0), (0,kh1), (1,kh0) -> 12 GLL; vmcnt(4) => tile0 ready
    STGA(0, 0, 0); STGB(0, 0, 0);
    STGA(0, 1, 0); STGB(0, 1, 0);
    {
        const int t1p = (1 < nt) ? 1 : 0;
        STGA(1, 0, t1p); STGB(1, 0, t1p);
    }
    VMC(4);
    SBAR;

    for (int kt = 0; kt < nt; ++kt) {
        const int db = kt & 1, sb = db ^ 1;
        const int t1c = (kt + 1 < nt) ? kt + 1 : nt - 1;   // data for (kh1)
        const int t2c = (kt + 2 < nt) ? kt + 2 : nt - 1;   // data for (kh0)
        // ---- P1 ----
        LDA8(db, 0);
        LDB1(db, 0, 0, 0); LDB1(db, 0, 1, 1);
        STGA(sb, 1, t1c);
        LGKM0;
        MMA2(0);
        SBAR;
        // ---- P2 ----
        LDB1(db, 0, 2, 2); LDB1(db, 0, 3, 3);
        STGB(sb, 1, t1c);
        LGKM0;
        MMA2(2);
        SBAR;
        // ---- P3 ----
        LDA8(db, 1);
        LDB1(db, 1, 0, 0); LDB1(db, 1, 1, 1);
        STGA(db, 0, t2c);
        LGKM0;
        MMA2(0);
        SBAR;
        // ---- P4 ----
        LDB1(db, 1, 2, 2); LDB1(db, 1, 3, 3);
        STGB(db, 0, t2c);
        LGKM0;
        MMA2(2);
        VMC(4);                 // guarantees through (kt+1,kh1); kh0 older
        SBAR;
    }
    VMC(0);                     // drain stray tail prefetches before exit

    const int rbase = (lane >> 4) << 2;
#pragma unroll
    for (int n = 0; n < 4; ++n) {
        const int gcol = (int)tile_n + wn * 64 + n * 16 + arow;
        const float s0 = p0[gcol];
        const float s1 = (EPI != 1) ? p1[gcol] : 0.f;
#pragma unroll
        for (int m = 0; m < 8; ++m) {
            const long grow0 = tile_m + wm * 128 + m * 16 + rbase;
            if (EPI == 4) {
                const long bb = grow0 >> 12, pix = grow0 & 4095;
                float4 o4;
#pragma unroll
                for (int r = 0; r < 4; ++r) {
                    float v = acc[m][n][r] * s0 + s1;
                    ((float*)&o4)[r] = fsilu(v);
                }
                *(float4*)&((float*)outp)[((bb * 512 + gcol)) * 4096 + pix] = o4;
            } else {
#pragma unroll
                for (int r = 0; r < 4; ++r) {
                    float v = acc[m][n][r];
                    if (EPI != 1) { v = v * s0 + s1; v = fsilu(v); }
                    else          { v += s0; }
                    ((unsigned short*)outp)[(grow0 + r) * ldo + gcol] = f2bf(v);
                }
            }
        }
    }
#undef PA0
#undef PA1
#undef PB0
#undef PB1
#undef STGA
#undef STGB
#undef LDA8
#undef LDB1
#undef MMA2
}

// ---------------------------------------------------------------------------
// gemm_pair: grid = 256 linear. Pair-XCD swizzle: the two n-tiles sharing an
// A-panel land on the same XCD (ids 8 apart). M = 128 m-tiles, N = 2.
// ---------------------------------------------------------------------------
template <int EPI, bool DUAL>
__global__ __launch_bounds__(512, 2) void gemm_pair(
    const unsigned short* __restrict__ A, const unsigned short* __restrict__ B,
    const unsigned short* __restrict__ A2, const unsigned short* __restrict__ B2,
    int lda, int ldb, int K1, int K2,
    void* __restrict__ outp, int ldo,
    const float* __restrict__ p0, const float* __restrict__ p1)
{
    __shared__ __align__(16) unsigned short Ash[2][2][8192];
    __shared__ __align__(16) unsigned short Bsh[2][2][8192];
    const int bid = blockIdx.x;
    const int xcd = bid & 7, idx = bid >> 3;
    const int m = xcd + 8 * (idx >> 1);
    const int n = idx & 1;
    gemm_core<EPI, DUAL>(Ash, Bsh, m, n, A, B, A2, B2, lda, ldb, K1, K2,
                         outp, ldo, p0, p1);
}

// ---------------------------------------------------------------------------
// gemm_wcv1: merged launch, 142 blocks. [0,14) = w2g (2x7 tiles, EPI=1),
// [14,142) = cv1 (128x1 tiles, EPI=0). Runs concurrently.
// ---------------------------------------------------------------------------
__global__ __launch_bounds__(512, 2) void gemm_wcv1(
    const unsigned short* __restrict__ wc2, const unsigned short* __restrict__ wvT,
    unsigned short* __restrict__ w2g, const float* __restrict__ zeros,
    const unsigned short* __restrict__ xT, const unsigned short* __restrict__ wb1,
    unsigned short* __restrict__ catT,
    const float* __restrict__ sc1, const float* __restrict__ sh1)
{
    __shared__ __align__(16) unsigned short Ash[2][2][8192];
    __shared__ __align__(16) unsigned short Bsh[2][2][8192];
    const int bid = blockIdx.x;
    if (bid < 14) {
        const int bx = bid / 7, by = bid % 7;
        gemm_core<1, false>(Ash, Bsh, bx, by, wc2, wvT, wc2, wvT,
                            1792, 1792, 1792, 0, w2g, 1792, zeros, nullptr);
    } else {
        const int bx = bid - 14;
        gemm_core<0, false>(Ash, Bsh, bx, 0, xT, wb1, xT, wb1,
                            512, 512, 512, 0, catT, 1792, sc1, sh1);
    }
}

// ---------------------------------------------------------------------------
// prep_all: one launch, 6416 blocks x 256 threads, partitioned:
//   [0,4096)    transpose_x  (8,512,4096) fp32 -> xT (32768,512) bf16
//   [4096,4880) transpose_w  v_w -> wvT bf16
//   [4880,5904) prep         weights->bf16, qk stack, cv1 BN, qkb, zeros
//   [5904,6416) sh2          dot(W2[i],b_v) reduce + BN shift
// ---------------------------------------------------------------------------
__global__ __launch_bounds__(256) void prep_all(
    const float* __restrict__ x, unsigned short* __restrict__ xT,
    const float* __restrict__ v_w, unsigned short* __restrict__ wvT,
    const float* __restrict__ cv1_w, const float* __restrict__ cv1_g,
    const float* __restrict__ cv1_b, const float* __restrict__ cv1_m,
    const float* __restrict__ cv1_v,
    const float* __restrict__ q_w, const float* __restrict__ q_b,
    const float* __restrict__ k_w, const float* __restrict__ k_b,
    const float* __restrict__ cv2_w,
    unsigned short* __restrict__ wb1, unsigned short* __restrict__ wqk,
    unsigned short* __restrict__ wc2,
    float* __restrict__ sc1, float* __restrict__ sh1,
    float* __restrict__ qkb, float* __restrict__ zeros,
    const float* __restrict__ cv2_g, const float* __restrict__ cv2_b,
    const float* __restrict__ cv2_m, const float* __restrict__ cv2_v,
    const float* __restrict__ v_b, const float* __restrict__ gamma,
    float* __restrict__ sc2, float* __restrict__ sh2)
{
    const int bid = blockIdx.x, tid = threadIdx.x;
    __shared__ __align__(16) float tile[64][65];
    if (bid < 4096) {
        int nt = bid & 63, ct = (bid >> 6) & 7, b = bid >> 9;
        int n0 = nt * 64, c0 = ct * 64;
#pragma unroll
        for (int it = 0; it < 16; ++it) {
            int idx = tid + it * 256;
            int r = idx >> 6, cc = idx & 63;
            tile[r][cc] = x[((long)(b * 512 + c0 + r)) * 4096 + n0 + cc];
        }
        __syncthreads();
#pragma unroll
        for (int it = 0; it < 16; ++it) {
            int idx = tid + it * 256;
            int r = idx >> 6, cc = idx & 63;
            xT[((long)(b * 4096 + n0 + r)) * 512 + c0 + cc] = f2bf(tile[cc][r]);
        }
    } else if (bid < 4880) {
        int id = bid - 4096;
        int tx = id % 28, ty = id / 28;
#pragma unroll
        for (int it = 0; it < 16; ++it) {
            int idx = tid + it * 256;
            int r = idx >> 6, cc = idx & 63;
            tile[r][cc] = v_w[((long)(ty * 64 + r)) * 1792 + tx * 64 + cc];
        }
        __syncthreads();
#pragma unroll
        for (int it = 0; it < 16; ++it) {
            int idx = tid + it * 256;
            int r = idx >> 6, cc = idx & 63;
            wvT[((long)(tx * 64 + r)) * 1792 + ty * 64 + cc] = f2bf(tile[cc][r]);
        }
    } else if (bid < 5904) {
        for (int i = (bid - 4880) * 256 + tid; i < 917504; i += 1024 * 256) {
            wc2[i] = f2bf(cv2_w[i]);
            int row = i / 1792;
            int col = i - row * 1792;
            float qv = (row < 224) ? q_w[i]
                       : (row < 448) ? k_w[(row - 224) * 1792 + col] : 0.f;
            wqk[i] = f2bf(qv);
            if (i < 131072) wb1[i] = f2bf(cv1_w[i]);
            if (i < 1792) zeros[i] = 0.f;
            if (i < 512) qkb[i] = (i < 224) ? q_b[i] : (i < 448 ? k_b[i - 224] : 0.f);
            if (i < 256) {
                float sc = cv1_g[i] * rsqrtf(cv1_v[i] + 1e-5f);
                sc1[i] = sc; sh1[i] = cv1_b[i] - cv1_m[i] * sc;
            }
        }
    } else {
        const int i = bid - 5904;
        float* red = &tile[0][0];
        float s = 0.f;
        for (int k = tid; k < 1792; k += 256) s += cv2_w[i * 1792 + k] * v_b[k];
        red[tid] = s;
        __syncthreads();
#pragma unroll
        for (int off = 128; off > 0; off >>= 1) {
            if (tid < off) red[tid] += red[tid + off];
            __syncthreads();
        }
        if (tid == 0) {
            float sc = cv2_g[i] * rsqrtf(cv2_v[i] + 1e-5f);
            sc2[i] = sc;
            sh2[i] = cv2_b[i] - cv2_m[i] * sc + sc * gamma[0] * red[0];
        }
    }
}

// ---------------------------------------------------------------------------
// pool_h body per radius (van Herk max + sliding sum along w).
// ---------------------------------------------------------------------------
template <int I>
DEV void pool_h_body(const unsigned short* x1s, unsigned short* pool,
                     int c, int w0, long obase)
{
    constexpr int R = 2 * (I + 1);
    constexpr int K = 2 * R + 1;
    unsigned short* qm = pool + (long)I * 32768 * 256;
    unsigned short* qs = pool + (long)(I + 3) * 32768 * 256;
    float pre[32];
    {
        float run = -1e30f;
        int ph = (w0 + 2 * R - (K - 1)) % K;
#pragma unroll
        for (int t = 0; t < 32 + K - 1; ++t) {
            int p = w0 + R - (K - 1) + t;
            if (ph == 0) run = -1e30f;
            float v = ((unsigned)p < 64u) ? bf2f(x1s[p * 256 + c]) : -1e30f;
            run = fmaxf(run, v);
            if (t >= K - 1) pre[t - (K - 1)] = run;
            ph = (ph + 1 == K) ? 0 : ph + 1;
        }
    }
    {
        float run = -1e30f;
        int ph = (w0 + 31 + (K - 1)) % K;
#pragma unroll
        for (int t = 0; t < 32 + K - 1; ++t) {
            int s = w0 + 31 - R + (K - 1) - t;
            if (ph == K - 1) run = -1e30f;
            float v = ((unsigned)s < 64u) ? bf2f(x1s[s * 256 + c]) : -1e30f;
            run = fmaxf(run, v);
            if (t >= K - 1) {
                int w = s + R;
                qm[obase + (long)w * 16384] =
                    f2bf(fmaxf(run, pre[31 + (K - 1) - t]));
            }
            ph = (ph == 0) ? K - 1 : ph - 1;
        }
    }
    {
        float s = 0.f;
        int lo0 = (w0 - R >= 0) ? w0 - R : 0;
        int hi0 = (w0 + R <= 63) ? w0 + R : 63;
        for (int d = lo0; d <= hi0; ++d) s += bf2f(x1s[d * 256 + c]);
        for (int ww = 0; ww < 32; ++ww) {
            int w = w0 + ww;
            qs[obase + (long)w * 16384] = f2bf(s);
            if (w + 1 + R <= 63) s += bf2f(x1s[(w + 1 + R) * 256 + c]);
            if (w - R >= 0)      s -= bf2f(x1s[(w - R) * 256 + c]);
        }
    }
}

__global__ __launch_bounds__(512) void pool_h_all(
    const unsigned short* __restrict__ catT, unsigned short* __restrict__ pool)
{
    const int b = blockIdx.x >> 6, h = blockIdx.x & 63;
    __shared__ __align__(16) unsigned short x1s[64 * 256];
    const int tid = threadIdx.x, lane = tid & 63, wave = tid >> 6;
    const long nb = (long)b * 4096 + h * 64;
#pragma unroll
    for (int j = 0; j < 4; ++j) {
        int chunk = j * 8 + wave;
        int o = chunk * 1024 + lane * 16;
        int e = o >> 1, w = e >> 8, c = e & 255;
        GLL(catT + (nb + w) * 1792 + c, (char*)x1s + chunk * 1024);
    }
    __syncthreads();
    const int c = tid & 255, wg = tid >> 8;
    const int w0 = wg * 32;
    const long obase = ((long)b * 4096 + h) * 256 + c;
    pool_h_body<0>(x1s, pool, c, w0, obase);
    pool_h_body<1>(x1s, pool, c, w0, obase);
    pool_h_body<2>(x1s, pool, c, w0, obase);
}

// ---------------------------------------------------------------------------
// pool_v body per radius; slabs staged by caller.
// ---------------------------------------------------------------------------
template <int I>
DEV void pool_v_body(const unsigned short* mslab, const unsigned short* sslab,
                     unsigned short* catT, int c, int h0, long dbase)
{
    constexpr int R = 2 * (I + 1);
    constexpr int K = 2 * R + 1;
    constexpr float SCL = (I == 0) ? (1.f / 25.f)
                        : (I == 1) ? (1.f / 81.f) : (1.f / 169.f);
    constexpr int MAXD = 256 * (I + 1);
    constexpr int SUMD = 1536 - 256 * I;
    float pre[32];
    {
        float run = -1e30f;
        int ph = (h0 + 2 * R - (K - 1)) % K;
#pragma unroll
        for (int t = 0; t < 32 + K - 1; ++t) {
            int p = h0 + R - (K - 1) + t;
            if (ph == 0) run = -1e30f;
            float v = ((unsigned)p < 64u) ? bf2f(mslab[p * 128 + c]) : -1e30f;
            run = fmaxf(run, v);
            if (t >= K - 1) pre[t - (K - 1)] = run;
            ph = (ph + 1 == K) ? 0 : ph + 1;
        }
    }
    {
        float run = -1e30f;
        int ph = (h0 + 31 + (K - 1)) % K;
#pragma unroll
        for (int t = 0; t < 32 + K - 1; ++t) {
            int s = h0 + 31 - R + (K - 1) - t;
            if (ph == K - 1) run = -1e30f;
            float v = ((unsigned)s < 64u) ? bf2f(mslab[s * 128 + c]) : -1e30f;
            run = fmaxf(run, v);
            if (t >= K - 1) {
                int h = s + R;
                catT[dbase + MAXD + (long)h * (64 * 1792)] =
                    f2bf(fmaxf(run, pre[31 + (K - 1) - t]));
            }
            ph = (ph == 0) ? K - 1 : ph - 1;
        }
    }
    {
        float s = 0.f;
        int lo0 = (h0 - R >= 0) ? h0 - R : 0;
        int hi0 = (h0 + R <= 63) ? h0 + R : 63;
        for (int d = lo0; d <= hi0; ++d) s += bf2f(sslab[d * 128 + c]);
        for (int hh = 0; hh < 32; ++hh) {
            int h = h0 + hh;
            catT[dbase + SUMD + (long)h * (64 * 1792)] = f2bf(s * SCL);
            if (h + 1 + R <= 63) s += bf2f(sslab[(h + 1 + R) * 128 + c]);
            if (h - R >= 0)      s -= bf2f(sslab[(h - R) * 128 + c]);
        }
    }
}

__global__ __launch_bounds__(256) void pool_v_all(
    const unsigned short* __restrict__ pool, unsigned short* __restrict__ catT)
{
    const int s6 = blockIdx.y;
    const int bid = blockIdx.x;
    const int chh = bid & 1, w = (bid >> 1) & 63, b = bid >> 7;
    const int c0 = chh * 128;
    __shared__ __align__(16) unsigned short mslab[64 * 128];
    __shared__ __align__(16) unsigned short sslab[64 * 128];
    const int tid = threadIdx.x, lane = tid & 63, wave = tid >> 6;
    const long sbase = ((long)b * 4096 + (long)w * 64) * 256 + c0;
    const unsigned short* msrc = pool + (long)s6 * 32768 * 256 + sbase;
    const unsigned short* ssrc = pool + (long)(s6 + 3) * 32768 * 256 + sbase;
#pragma unroll
    for (int j = 0; j < 4; ++j) {
        int o = j * 4096 + wave * 1024 + lane * 16;
        int hh = o >> 8, ce = (o & 255) >> 1;
        GLL(msrc + hh * 256 + ce, (char*)mslab + (j * 4096 + wave * 1024));
        GLL(ssrc + hh * 256 + ce, (char*)sslab + (j * 4096 + wave * 1024));
    }
    __syncthreads();
    const int c = tid & 127, hg = tid >> 7;
    const int h0 = hg * 32;
    const long dbase = ((long)b * 4096 + w) * 1792 + c0 + c;
    if (s6 == 0)      pool_v_body<0>(mslab, sslab, catT, c, h0, dbase);
    else if (s6 == 1) pool_v_body<1>(mslab, sslab, catT, c, h0, dbase);
    else              pool_v_body<2>(mslab, sslab, catT, c, h0, dbase);
}

// ---------------------------------------------------------------------------
// S1: eH scores, block = (b, w).
// ---------------------------------------------------------------------------
__global__ __launch_bounds__(256) void scores_h(
    const unsigned short* __restrict__ qk, float* __restrict__ attHlog)
{
    const int b = blockIdx.x >> 6, w = blockIdx.x & 63;
    __shared__ __align__(16) unsigned short Qs[64 * 232];
    __shared__ __align__(16) unsigned short Ks[64 * 232];
    const int tid = threadIdx.x, lane = tid & 63, wave = tid >> 6;
#pragma unroll
    for (int j = 0; j < 14; ++j) {
        int idx = tid + j * 256;
        int s = idx >= 1792;
        int id2 = idx - s * 1792;
        int row = id2 / 28, cb = id2 - row * 28;
        bf16x8 v = *(const bf16x8*)(qk + ((long)b * 4096 + row * 64 + w) * 512 +
                                    s * 224 + cb * 8);
        *(bf16x8*)((s ? Ks : Qs) + row * 232 + cb * 8) = v;
    }
    __syncthreads();
    const int m0 = wave * 16, arow = lane & 15, kc = (lane >> 4) << 3;
    f32x4 acc[4] = {};
#pragma unroll
    for (int ks = 0; ks < 7; ++ks) {
        bf16x8 af = *(const bf16x8*)(Qs + (m0 + arow) * 232 + ks * 32 + kc);
#pragma unroll
        for (int nf = 0; nf < 4; ++nf) {
            bf16x8 bv = *(const bf16x8*)(Ks + (nf * 16 + arow) * 232 + ks * 32 + kc);
            acc[nf] = MFMA(af, bv, acc[nf]);
        }
    }
    const int rb = (lane >> 4) << 2;
#pragma unroll
    for (int nf = 0; nf < 4; ++nf) {
        int g = nf * 16 + arow;
#pragma unroll
        for (int r = 0; r < 4; ++r) {
            int h = m0 + rb + r;
            float v = acc[nf][r];
            if (g == h) v = -1e30f;
            attHlog[((long)(b * 64 + h) * 64 + w) * 64 + g] = v;
        }
    }
}

// ---------------------------------------------------------------------------
// S2: eW scores + fused softmax over concat([eH, eW], 128). block = (b, h).
// ---------------------------------------------------------------------------
__global__ __launch_bounds__(256) void scores_w_softmax(
    const unsigned short* __restrict__ qk, const float* __restrict__ attHlog,
    unsigned short* __restrict__ att)
{
    const int b = blockIdx.x >> 6, h = blockIdx.x & 63;
    __shared__ __align__(16) unsigned short Qs[64 * 232];
    __shared__ __align__(16) unsigned short Ks[64 * 232];
    __shared__ float ews[64 * 65];
    const int tid = threadIdx.x, lane = tid & 63, wave = tid >> 6;
    const long nbase = (long)b * 4096 + h * 64;
#pragma unroll
    for (int j = 0; j < 14; ++j) {
        int idx = tid + j * 256;
        int s = idx >= 1792;
        int id2 = idx - s * 1792;
        int row = id2 / 28, cb = id2 - row * 28;
        bf16x8 v = *(const bf16x8*)(qk + (nbase + row) * 512 + s * 224 + cb * 8);
        *(bf16x8*)((s ? Ks : Qs) + row * 232 + cb * 8) = v;
    }
    __syncthreads();
    const int m0 = wave * 16, arow = lane & 15, kc = (lane >> 4) << 3;
    f32x4 acc[4] = {};
#pragma unroll
    for (int ks = 0; ks < 7; ++ks) {
        bf16x8 af = *(const bf16x8*)(Qs + (m0 + arow) * 232 + ks * 32 + kc);
#pragma unroll
        for (int nf = 0; nf < 4; ++nf) {
            bf16x8 bv = *(const bf16x8*)(Ks + (nf * 16 + arow) * 232 + ks * 32 + kc);
            acc[nf] = MFMA(af, bv, acc[nf]);
        }
    }
    const int rb = (lane >> 4) << 2;
#pragma unroll
    for (int nf = 0; nf < 4; ++nf)
#pragma unroll
        for (int r = 0; r < 4; ++r)
            ews[(m0 + rb + r) * 65 + nf * 16 + arow] = acc[nf][r];
    __syncthreads();
    const int wl = tid >> 2, p = tid & 3;
    float eh[16], ew[16];
    const float* hrow = attHlog + ((long)(b * 64 + h) * 64 + wl) * 64 + p * 16;
#pragma unroll
    for (int j = 0; j < 16; ++j) eh[j] = hrow[j];
#pragma unroll
    for (int j = 0; j < 16; ++j) ew[j] = ews[wl * 65 + p * 16 + j];
    float mx = -1e30f;
#pragma unroll
    for (int j = 0; j < 16; ++j) { mx = fmaxf(mx, eh[j]); mx = fmaxf(mx, ew[j]); }
    mx = fmaxf(mx, __shfl_xor(mx, 1));
    mx = fmaxf(mx, __shfl_xor(mx, 2));
    float sm = 0.f;
#pragma unroll
    for (int j = 0; j < 16; ++j) {
        eh[j] = __expf(eh[j] - mx); sm += eh[j];
        ew[j] = __expf(ew[j] - mx); sm += ew[j];
    }
    sm += __shfl_xor(sm, 1);
    sm += __shfl_xor(sm, 2);
    float inv = 1.f / sm;
    unsigned short* orow = att + ((long)(b * 64 + h) * 64 + wl) * 128;
#pragma unroll
    for (int j = 0; j < 16; ++j) orow[p * 16 + j] = f2bf(eh[j] * inv);
#pragma unroll
    for (int j = 0; j < 16; ++j) orow[64 + p * 16 + j] = f2bf(ew[j] * inv);
}

// ---------------------------------------------------------------------------
// apply_att on cat directly: grid 2048 = b(8) x i(64) x chunk(4).
//   MODE 0: mixed = attH-mix(cat).   MODE 1: mixed = gam*(mixed + attW-mix).
// ---------------------------------------------------------------------------
template <int MODE>
__global__ __launch_bounds__(256) void apply_att(
    const unsigned short* __restrict__ att, const unsigned short* __restrict__ vsrc,
    unsigned short* __restrict__ mixed, const float* __restrict__ gamma)
{
    const int ch = blockIdx.x & 3;
    const int i  = (blockIdx.x >> 2) & 63;
    const int b  = blockIdx.x >> 8;
    const int c0 = ch * 448;
    __shared__ __align__(16) unsigned short As[64 * 72];
    __shared__ __align__(16) unsigned short Vs[64 * 448];
    const int tid = threadIdx.x, lane = tid & 63, wave = tid >> 6;
#pragma unroll
    for (int j = 0; j < 2; ++j) {
        int idx = tid + j * 256;
        int hh = idx >> 3, cb = idx & 7;
        long pos = (MODE == 0) ? ((long)(b * 64 + hh) * 64 + i)
                               : ((long)(b * 64 + i) * 64 + hh);
        bf16x8 v = *(const bf16x8*)(att + pos * 128 + MODE * 64 + cb * 8);
        *(bf16x8*)(As + hh * 72 + cb * 8) = v;
    }
#pragma unroll
    for (int j = 0; j < 14; ++j) {
        int idx = tid + j * 256;
        int g = idx / 56, cb = idx - g * 56;
        long n = (MODE == 0) ? ((long)b * 4096 + g * 64 + i)
                             : ((long)b * 4096 + i * 64 + g);
        bf16x8 v = *(const bf16x8*)(vsrc + n * 1792 + c0 + cb * 8);
        int sw = (g >> 3) & 7;
        *(bf16x8*)(Vs + g * 448 + ((cb ^ sw) << 3)) = v;
    }
    __syncthreads();
    const int arow = lane & 15, kc8 = (lane >> 4) << 3;
    const int rb = (lane >> 4) << 2;
    f32x4 acc[4][7] = {};
#pragma unroll
    for (int ks = 0; ks < 2; ++ks) {
        const int k0 = ks * 32;
        bf16x8 af[4];
#pragma unroll
        for (int m = 0; m < 4; ++m)
            af[m] = *(const bf16x8*)(As + (m * 16 + arow) * 72 + k0 + kc8);
        const int g0 = k0 + kc8;
        const int sw = (g0 >> 3) & 7;
#pragma unroll
        for (int nf = 0; nf < 7; ++nf) {
            int cl = wave * 112 + nf * 16 + arow;
            int cb = cl >> 3, clo = cl & 7;
            const unsigned short* pp = Vs + g0 * 448 + ((cb ^ sw) << 3) + clo;
            bf16x8 bv;
#pragma unroll
            for (int j = 0; j < 8; ++j) bv[j] = (short)pp[j * 448];
#pragma unroll
            for (int m = 0; m < 4; ++m)
                acc[m][nf] = MFMA(af[m], bv, acc[m][nf]);
        }
    }
    const float gam = gamma[0];
#pragma unroll
    for (int nf = 0; nf < 7; ++nf) {
        const int c = c0 + wave * 112 + nf * 16 + arow;
#pragma unroll
        for (int m = 0; m < 4; ++m) {
#pragma unroll
            for (int r = 0; r < 4; ++r) {
                const int rl = m * 16 + rb + r;
                long n = (MODE == 0) ? ((long)b * 4096 + rl * 64 + i)
                                     : ((long)b * 4096 + i * 64 + rl);
                long idx2 = n * 1792 + c;
                if (MODE == 0) {
                    mixed[idx2] = f2bf(acc[m][nf][r]);
                } else {
                    float pv = bf2f(mixed[idx2]);
                    mixed[idx2] = f2bf(gam * (acc[m][nf][r] + pv));
                }
            }
        }
    }
}

// ---------------------------------------------------------------------------
// launcher
// ---------------------------------------------------------------------------
extern "C" void kernel_launch(void* const* d_in, const int* in_sizes, int n_in,
                              void* d_out, int out_size, void* d_ws, size_t ws_size,
                              hipStream_t stream)
{
    const float* x     = (const float*)d_in[0];
    const float* cv1_w = (const float*)d_in[1];
    const float* cv1_g = (const float*)d_in[2];
    const float* cv1_b = (const float*)d_in[3];
    const float* cv1_m = (const float*)d_in[4];
    const float* cv1_v = (const float*)d_in[5];
    const float* q_w   = (const float*)d_in[6];
    const float* q_b   = (const float*)d_in[7];
    const float* k_w   = (const float*)d_in[8];
    const float* k_b   = (const float*)d_in[9];
    const float* v_w   = (const float*)d_in[10];
    const float* v_b   = (const float*)d_in[11];
    const float* gamma = (const float*)d_in[12];
    const float* cv2_w = (const float*)d_in[13];
    const float* cv2_g = (const float*)d_in[14];
    const float* cv2_b = (const float*)d_in[15];
    const float* cv2_m = (const float*)d_in[16];
    const float* cv2_v = (const float*)d_in[17];

    char* ws = (char*)d_ws;
    // ---- workspace map (total ~230 MiB) ----
    unsigned short* wb1  = (unsigned short*)(ws + 0);          //  256x512
    unsigned short* wqk  = (unsigned short*)(ws + 262144);     //  512x1792
    unsigned short* wc2  = (unsigned short*)(ws + 2097152);    //  512x1792
    unsigned short* w2g  = (unsigned short*)(ws + 3932160);    //  512x1792 (W2*Wv)
    float* sc1           = (float*)(ws + 5767168);
    float* sh1           = (float*)(ws + 5775360);
    float* sc2           = (float*)(ws + 5783552);
    float* sh2           = (float*)(ws + 5791744);
    float* qkb           = (float*)(ws + 5799936);
    float* zeros         = (float*)(ws + 5808128);             // 1792 fp32
    unsigned short* catT = (unsigned short*)(ws + 6291456);    // 32768x1792, live to end
    const long C_OFF = 123731968;                              // catT end
    unsigned short* xT    = (unsigned short*)(ws + C_OFF);            // ph1: 32 MiB
    unsigned short* wvT   = (unsigned short*)(ws + C_OFF + 33554432); // ph1: 6.1 MiB
    unsigned short* poolb = (unsigned short*)(ws + C_OFF);            // ph2: 96 MiB
    unsigned short* mixed = (unsigned short*)(ws + C_OFF);            // ph3-4: 112 MiB
    // d_out (64 MB) time-shared: qk[0,32M) + attHlog[32M,40M) + attb[40M,48M)
    unsigned short* qk    = (unsigned short*)d_out;
    float* attHlog        = (float*)((char*)d_out + 33554432);
    unsigned short* attb  = (unsigned short*)((char*)d_out + 41943040);

    // all independent preprocessing in ONE launch
    prep_all<<<6416, 256, 0, stream>>>(
        x, xT, v_w, wvT,
        cv1_w, cv1_g, cv1_b, cv1_m, cv1_v, q_w, q_b, k_w, k_b, cv2_w,
        wb1, wqk, wc2, sc1, sh1, qkb, zeros,
        cv2_g, cv2_b, cv2_m, cv2_v, v_b, gamma, sc2, sh2);

    // w2g (14 blocks) runs concurrently with cv1 (128 blocks)
    gemm_wcv1<<<142, 512, 0, stream>>>(wc2, wvT, w2g, zeros,
                                       xT, wb1, catT, sc1, sh1);

    pool_h_all<<<512, 512, 0, stream>>>(catT, poolb);
    pool_v_all<<<dim3(1024, 3), 256, 0, stream>>>(poolb, catT);

    // q,k (stacked, padded to 512 cols) -> qk (in d_out); pair-XCD swizzle
    gemm_pair<1, false><<<256, 512, 0, stream>>>(
        catT, wqk, catT, wqk, 1792, 1792, 1792, 0, qk, 512, qkb, nullptr);

    scores_h<<<512, 256, 0, stream>>>(qk, attHlog);
    scores_w_softmax<<<512, 256, 0, stream>>>(qk, attHlog, attb);

    // criss-cross applied to cat itself -> mixed = gam*(mixH + mixW)
    apply_att<0><<<2048, 256, 0, stream>>>(attb, catT, mixed, gamma);
    apply_att<1><<<2048, 256, 0, stream>>>(attb, catT, mixed, gamma);

    // out = silu(bn( W2Wv.mixed + W2.cat )) -> NCHW fp32; pair-XCD swizzle
    gemm_pair<4, true><<<256, 512, 0, stream>>>(
        mixed, w2g, catT, wc2, 1792, 1792, 1792, 1792, d_out, 0, sc2, sh2);
}